// Round 2
// baseline (71501.025 us; speedup 1.0000x reference)
//
#include <hip/hip_runtime.h>
#include <cstdint>
#include <cstddef>

#define WIDTH 4096
#define DEPTH 512
#define NHIST 20
#define NS 64
#define NWG 256
#define NTHR 512

typedef __attribute__((ext_vector_type(4))) float f32x4;
typedef __attribute__((ext_vector_type(8))) short bf16x8;

__device__ __forceinline__ ushort f2bf(float f) {
    uint32_t u = __float_as_uint(f);
    u += 0x7FFFu + ((u >> 16) & 1u);   // round-to-nearest-even
    return (ushort)(u >> 16);
}

__device__ __forceinline__ void async_copy16(const void* g, void* l) {
    __builtin_amdgcn_global_load_lds(
        (const __attribute__((address_space(1))) uint32_t*)g,
        (__attribute__((address_space(3))) uint32_t*)l, 16, 0, 0);
}

// ---------------- bias GEMM, fp32 vector ALU ----------------
// C[n][i] = dot(biases[n,:], W_bias[i,:])   n in [0,512), i in [0,4096)
__global__ __launch_bounds__(256) void bias_gemm_kernel(const float* __restrict__ A,
                                                        const float* __restrict__ B,
                                                        float* __restrict__ C) {
    __shared__ float As[64][36];
    __shared__ float Bs[64][36];
    const int bm = blockIdx.y;
    const int bn = blockIdx.x;
    const int t  = threadIdx.x;
    const int tx = t & 15, ty = t >> 4;
    const int lr = t >> 3;
    const int lc = (t & 7) * 4;

    float acc[4][4] = {};
    for (int k0 = 0; k0 < WIDTH; k0 += 32) {
        float4 a0 = *(const float4*)&A[(size_t)(bm * 64 + lr) * WIDTH + k0 + lc];
        float4 a1 = *(const float4*)&A[(size_t)(bm * 64 + lr + 32) * WIDTH + k0 + lc];
        float4 b0 = *(const float4*)&B[(size_t)(bn * 64 + lr) * WIDTH + k0 + lc];
        float4 b1 = *(const float4*)&B[(size_t)(bn * 64 + lr + 32) * WIDTH + k0 + lc];
        __syncthreads();
        *(float4*)&As[lr][lc] = a0;  *(float4*)&As[lr + 32][lc] = a1;
        *(float4*)&Bs[lr][lc] = b0;  *(float4*)&Bs[lr + 32][lc] = b1;
        __syncthreads();
        #pragma unroll
        for (int k = 0; k < 32; k += 4) {
            float4 av[4], bv[4];
            #pragma unroll
            for (int mi = 0; mi < 4; mi++) av[mi] = *(const float4*)&As[ty * 4 + mi][k];
            #pragma unroll
            for (int ni = 0; ni < 4; ni++) bv[ni] = *(const float4*)&Bs[tx * 4 + ni][k];
            #pragma unroll
            for (int mi = 0; mi < 4; mi++)
                #pragma unroll
                for (int ni = 0; ni < 4; ni++)
                    acc[mi][ni] += av[mi].x * bv[ni].x + av[mi].y * bv[ni].y +
                                   av[mi].z * bv[ni].z + av[mi].w * bv[ni].w;
        }
    }
    #pragma unroll
    for (int mi = 0; mi < 4; mi++) {
        float4 v = make_float4(acc[mi][0], acc[mi][1], acc[mi][2], acc[mi][3]);
        *(float4*)&C[(size_t)(bm * 64 + ty * 4 + mi) * WIDTH + bn * 64 + tx * 4] = v;
    }
}

// ---------------- persistent reservoir kernel ----------------
// curr layout (blocked): element (row s, col n) at [(n>>3)*64 + s]*8 + (n&7)
//   -> k-slice j = bytes [j*65536, (j+1)*65536), contiguous, global_load_lds-able.
// WG (t,j): t = N-tile (128 cols), j = K-slice (512). wave (nh,kh): 64 cols x 128 k.
__global__ __launch_bounds__(NTHR, 2) void reservoir_kernel(
    const float* __restrict__ x,
    const float* __restrict__ W,
    const float* __restrict__ scales,
    const float* __restrict__ b,      // [512][4096] fp32
    float* __restrict__ out,          // [64][20][4096] fp32
    float* __restrict__ pbuf,         // [8 j][32 t][64 m][128 n] fp32
    ushort* __restrict__ cur0,
    ushort* __restrict__ cur1,
    int* sync_mem)
{
    __shared__ char smem[65536];      // A-slice 64KB; fp32 partial overlays [0,32K) post-MFMA

    const int tid  = threadIdx.x;
    const int wave = tid >> 6;
    const int lane = tid & 63;
    const int lrow = lane & 15;
    const int lq   = lane >> 4;
    const int nh   = wave & 1;
    const int kh   = wave >> 1;

    const int bid = blockIdx.x;
    const int xcd = bid & 7;          // heuristic XCD id (perf only)
    const int m_  = bid >> 3;
    const int q   = m_ >> 3;          // 0..3
    const int j   = m_ & 7;           // K-slice
    const int t   = xcd + 8 * q;      // N-tile; the 8 j-WGs of a tile share bid%8

    int* flag = sync_mem;             // [0]
    int* gcnt = sync_mem + 16;        // own cacheline
    int* cntA = sync_mem + 64;        // cntA[t] at +64 + t*32 (128B apart)

    // ---- init sync vars (ws is poisoned 0xAA every launch) ----
    if (bid == 0 && tid == 0) {
        *gcnt = 0;
        for (int i = 0; i < 32; i++) cntA[i * 32] = 0;
        __threadfence();
        __hip_atomic_store(flag, 0x1357ACE5, __ATOMIC_RELEASE, __HIP_MEMORY_SCOPE_AGENT);
    }
    if (tid == 0) {
        while (__hip_atomic_load(flag, __ATOMIC_RELAXED, __HIP_MEMORY_SCOPE_AGENT) != 0x1357ACE5)
            __builtin_amdgcn_s_sleep(2);
        (void)__hip_atomic_load(flag, __ATOMIC_ACQUIRE, __HIP_MEMORY_SCOPE_AGENT);
    }
    __syncthreads();

    // ---- load this wave's W block into registers (fp32 -> bf16 frags) ----
    const int nbase = t * 128 + nh * 64;
    const int kbase = j * 512 + kh * 128;
    bf16x8 wf[4][4];   // [nb][kc]
    #pragma unroll
    for (int nb = 0; nb < 4; nb++) {
        #pragma unroll
        for (int kc = 0; kc < 4; kc++) {
            const float* src = W + (size_t)(nbase + nb * 16 + lrow) * WIDTH + kbase + kc * 32 + lq * 8;
            float4 f0 = *(const float4*)src;
            float4 f1 = *(const float4*)(src + 4);
            bf16x8 v;
            v[0] = (short)f2bf(f0.x); v[1] = (short)f2bf(f0.y);
            v[2] = (short)f2bf(f0.z); v[3] = (short)f2bf(f0.w);
            v[4] = (short)f2bf(f1.x); v[5] = (short)f2bf(f1.y);
            v[6] = (short)f2bf(f1.z); v[7] = (short)f2bf(f1.w);
            wf[nb][kc] = v;
        }
    }

    // ---- init curr0 = tile(x), blocked layout; bids 0..7 fill slice j'=bid ----
    if (bid < 8) {
        for (int u = tid; u < 4096; u += NTHR) {       // unit16 index within slice
            int kv = u >> 6, row = u & 63;
            int colb = (bid * 64 + kv) * 8;
            ushort tmp[8];
            #pragma unroll
            for (int i2 = 0; i2 < 8; i2++) tmp[i2] = f2bf(x[colb + i2]);
            ushort* dst = cur0 + ((size_t)(bid * 64 + kv) * 64 + row) * 8;
            ushort4 lo, hi;
            lo.x = tmp[0]; lo.y = tmp[1]; lo.z = tmp[2]; lo.w = tmp[3];
            hi.x = tmp[4]; hi.y = tmp[5]; hi.z = tmp[6]; hi.w = tmp[7];
            *(ushort4*)dst = lo;
            *(ushort4*)(dst + 4) = hi;
        }
    }

    int epoch = 1;
    auto gbar = [&]() {
        __threadfence();
        __syncthreads();
        if (tid == 0) {
            __hip_atomic_fetch_add(gcnt, 1, __ATOMIC_ACQ_REL, __HIP_MEMORY_SCOPE_AGENT);
            int tgt = NWG * epoch;
            while (__hip_atomic_load(gcnt, __ATOMIC_RELAXED, __HIP_MEMORY_SCOPE_AGENT) < tgt)
                __builtin_amdgcn_s_sleep(2);
            (void)__hip_atomic_load(gcnt, __ATOMIC_ACQUIRE, __HIP_MEMORY_SCOPE_AGENT);
        }
        __syncthreads();
        epoch++;
    };

    gbar();   // curr0 + sync init complete

    ushort* curs[2] = {cur0, cur1};
    float* partial = (float*)smem;             // [64][128], overlays A-slice
    float* pdst = pbuf + ((size_t)j * 32 + t) * 8192;

    for (int d = 0; d < DEPTH; d++) {
        const ushort* cin = curs[d & 1];
        ushort* cout = curs[(d + 1) & 1];

        // ---- stage A-slice j (64KB, contiguous) into LDS ----
        {
            const ushort* src = cin + (size_t)j * 32768;
            #pragma unroll
            for (int it = 0; it < 8; it++) {
                int i2 = wave * 8 + it;                       // instr 0..63
                async_copy16(src + (size_t)i2 * 512 + lane * 8, smem + i2 * 1024);
            }
        }
        __syncthreads();   // drains vmcnt -> A-slice ready

        // ---- MFMA: 4 kc x (4 ds_read_b128 + 16 mfma) ----
        f32x4 acc[4][4];
        #pragma unroll
        for (int mb = 0; mb < 4; mb++)
            #pragma unroll
            for (int nb = 0; nb < 4; nb++)
                acc[mb][nb] = (f32x4){0.f, 0.f, 0.f, 0.f};

        #pragma unroll
        for (int kc = 0; kc < 4; kc++) {
            const int kvl = kh * 16 + kc * 4 + lq;
            bf16x8 af[4];
            #pragma unroll
            for (int mb = 0; mb < 4; mb++)
                af[mb] = *(const bf16x8*)(smem + ((size_t)kvl * 64 + mb * 16 + lrow) * 16);
            #pragma unroll
            for (int mb = 0; mb < 4; mb++)
                #pragma unroll
                for (int nb = 0; nb < 4; nb++)
                    acc[mb][nb] = __builtin_amdgcn_mfma_f32_16x16x32_bf16(af[mb], wf[nb][kc], acc[mb][nb], 0, 0, 0);
        }
        __syncthreads();   // all ds_reads done before partial overlays smem

        // ---- WG reduce over kh: kh==0 stores, kh>0 atomic-adds ----
        // C/D layout: n = lane&15, m = (lane>>4)*4 + r  [m89/m91]
        if (kh == 0) {
            #pragma unroll
            for (int mb = 0; mb < 4; mb++)
                #pragma unroll
                for (int nb = 0; nb < 4; nb++)
                    #pragma unroll
                    for (int r = 0; r < 4; r++)
                        partial[(mb * 16 + lq * 4 + r) * 128 + nh * 64 + nb * 16 + lrow] = acc[mb][nb][r];
        }
        __syncthreads();
        if (kh != 0) {
            #pragma unroll
            for (int mb = 0; mb < 4; mb++)
                #pragma unroll
                for (int nb = 0; nb < 4; nb++)
                    #pragma unroll
                    for (int r = 0; r < 4; r++)
                        atomicAdd(&partial[(mb * 16 + lq * 4 + r) * 128 + nh * 64 + nb * 16 + lrow],
                                  acc[mb][nb][r]);
        }
        __syncthreads();

        // ---- write 32KB fp32 partial to global ----
        for (int i4 = tid; i4 < 2048; i4 += NTHR)
            *(float4*)(pdst + (size_t)i4 * 4) = *(const float4*)(partial + (size_t)i4 * 4);
        __threadfence();
        __syncthreads();

        // ---- join the 8 K-slices of tile t (XCD-local by bid%8 heuristic) ----
        if (tid == 0) {
            __hip_atomic_fetch_add(&cntA[t * 32], 1, __ATOMIC_ACQ_REL, __HIP_MEMORY_SCOPE_AGENT);
            int tgt = 8 * (d + 1);
            while (__hip_atomic_load(&cntA[t * 32], __ATOMIC_RELAXED, __HIP_MEMORY_SCOPE_AGENT) < tgt)
                __builtin_amdgcn_s_sleep(2);
            (void)__hip_atomic_load(&cntA[t * 32], __ATOMIC_ACQUIRE, __HIP_MEMORY_SCOPE_AGENT);
        }
        __syncthreads();

        // ---- epilogue: this WG's 16-col stripe of tile t ----
        {
            const int cbase = t * 128 + j * 16;
            const int h = d - (DEPTH - NHIST);
            #pragma unroll
            for (int e = tid; e < 1024; e += NTHR) {
                int m = e >> 4;
                int c = e & 15;
                int col = cbase + c;
                float sum = 0.f;
                #pragma unroll
                for (int jj = 0; jj < 8; jj++)
                    sum += pbuf[(((size_t)jj * 32 + t) * 64 + m) * 128 + j * 16 + c];
                float pre = scales[m] * sum + b[(size_t)d * WIDTH + col];
                float v = erff(pre) * 0.015625f;
                cout[((size_t)(col >> 3) * 64 + m) * 8 + (col & 7)] = f2bf(v);
                if (h >= 0) out[((size_t)m * NHIST + h) * WIDTH + col] = v;
            }
        }

        gbar();   // step boundary: publishes cout, protects pbuf WAR
    }
}

extern "C" void kernel_launch(void* const* d_in, const int* in_sizes, int n_in,
                              void* d_out, int out_size, void* d_ws, size_t ws_size,
                              hipStream_t stream) {
    const float* x      = (const float*)d_in[0];
    const float* biases = (const float*)d_in[1];
    const float* W      = (const float*)d_in[2];
    const float* W_bias = (const float*)d_in[3];
    const float* scales = (const float*)d_in[4];
    float* out = (float*)d_out;

    char* ws = (char*)d_ws;
    float*  b    = (float*)ws;                                    // 8 MB
    float*  pbuf = (float*)(ws + ((size_t)8 << 20));              // 8 MB
    ushort* cur0 = (ushort*)(ws + ((size_t)16 << 20));            // 512 KB
    ushort* cur1 = (ushort*)(ws + ((size_t)16 << 20) + (512 << 10));
    int*    syncp = (int*)(ws + ((size_t)17 << 20));              // ~4.5 KB

    bias_gemm_kernel<<<dim3(64, 8), 256, 0, stream>>>(biases, W_bias, b);

    void* args[] = {(void*)&x, (void*)&W, (void*)&scales, (void*)&b, (void*)&out,
                    (void*)&pbuf, (void*)&cur0, (void*)&cur1, (void*)&syncp};
    hipLaunchCooperativeKernel((const void*)reservoir_kernel, dim3(NWG), dim3(NTHR),
                               args, 0, stream);
}

// Round 3
// 23994.949 us; speedup vs baseline: 2.9798x; 2.9798x over previous
//
#include <hip/hip_runtime.h>
#include <cstdint>
#include <cstddef>

#define WIDTH 4096
#define DEPTH 512
#define NHIST 20

typedef __attribute__((ext_vector_type(4))) float f32x4;
typedef __attribute__((ext_vector_type(8))) short bf16x8;

__device__ __forceinline__ ushort f2bf(float f) {
    uint32_t u = __float_as_uint(f);
    u += 0x7FFFu + ((u >> 16) & 1u);   // round-to-nearest-even
    return (ushort)(u >> 16);
}

__device__ __forceinline__ void async_copy16(const void* g, void* l) {
    __builtin_amdgcn_global_load_lds(
        (const __attribute__((address_space(1))) uint32_t*)g,
        (__attribute__((address_space(3))) uint32_t*)l, 16, 0, 0);
}

// ---------------- W fp32 -> Wb bf16, fragment-major blocked layout ----------
// Wb unit8 index u = (((t*8 + j)*8 + wave)*16 + (nb*4+kc))*64 + lane, holding
// bf16(W[n][k + 0..7]) with n = t*128 + nh*64 + nb*16 + (lane&15),
// k = j*512 + kh*128 + kc*32 + (lane>>4)*8, wave = kh*2 + nh.
__global__ __launch_bounds__(256) void convert_w_kernel(const float* __restrict__ W,
                                                        ushort* __restrict__ Wb) {
    uint32_t u = blockIdx.x * 256 + threadIdx.x;     // 0 .. 2^21-1
    uint32_t lane = u & 63;
    uint32_t fr   = (u >> 6) & 15;
    uint32_t wv   = (u >> 10) & 7;
    uint32_t j    = (u >> 13) & 7;
    uint32_t t    = u >> 16;
    uint32_t nb = fr >> 2, kc = fr & 3;
    uint32_t nh = wv & 1,  kh = wv >> 1;
    uint32_t n = t * 128 + nh * 64 + nb * 16 + (lane & 15);
    uint32_t k = j * 512 + kh * 128 + kc * 32 + (lane >> 4) * 8;
    const float* src = W + (size_t)n * WIDTH + k;
    float4 f0 = *(const float4*)src;
    float4 f1 = *(const float4*)(src + 4);
    ushort4 lo, hi;
    lo.x = f2bf(f0.x); lo.y = f2bf(f0.y); lo.z = f2bf(f0.z); lo.w = f2bf(f0.w);
    hi.x = f2bf(f1.x); hi.y = f2bf(f1.y); hi.z = f2bf(f1.z); hi.w = f2bf(f1.w);
    ushort* dst = Wb + (size_t)u * 8;
    *(ushort4*)dst = lo;
    *(ushort4*)(dst + 4) = hi;
}

// ---------------- curr0 = tile(x), blocked bf16 layout ----------------------
// cur element (m, c) at (( (c>>3)*64 + m )*8 + (c&7))
__global__ __launch_bounds__(256) void init_curr_kernel(const float* __restrict__ x,
                                                        ushort* __restrict__ cur) {
    int g = blockIdx.x * 256 + threadIdx.x;   // 0..32767
    int kv = g >> 6, m = g & 63;
    ushort4 lo, hi;
    lo.x = f2bf(x[kv * 8 + 0]); lo.y = f2bf(x[kv * 8 + 1]);
    lo.z = f2bf(x[kv * 8 + 2]); lo.w = f2bf(x[kv * 8 + 3]);
    hi.x = f2bf(x[kv * 8 + 4]); hi.y = f2bf(x[kv * 8 + 5]);
    hi.z = f2bf(x[kv * 8 + 6]); hi.w = f2bf(x[kv * 8 + 7]);
    ushort* dst = cur + ((size_t)kv * 64 + m) * 8;
    *(ushort4*)dst = lo;
    *(ushort4*)(dst + 4) = hi;
}

// ---------------- bias GEMM, fp32 vector ALU --------------------------------
__global__ __launch_bounds__(256) void bias_gemm_kernel(const float* __restrict__ A,
                                                        const float* __restrict__ B,
                                                        float* __restrict__ C) {
    __shared__ float As[64][36];
    __shared__ float Bs[64][36];
    const int bm = blockIdx.y;
    const int bn = blockIdx.x;
    const int t  = threadIdx.x;
    const int tx = t & 15, ty = t >> 4;
    const int lr = t >> 3;
    const int lc = (t & 7) * 4;

    float acc[4][4] = {};
    for (int k0 = 0; k0 < WIDTH; k0 += 32) {
        float4 a0 = *(const float4*)&A[(size_t)(bm * 64 + lr) * WIDTH + k0 + lc];
        float4 a1 = *(const float4*)&A[(size_t)(bm * 64 + lr + 32) * WIDTH + k0 + lc];
        float4 b0 = *(const float4*)&B[(size_t)(bn * 64 + lr) * WIDTH + k0 + lc];
        float4 b1 = *(const float4*)&B[(size_t)(bn * 64 + lr + 32) * WIDTH + k0 + lc];
        __syncthreads();
        *(float4*)&As[lr][lc] = a0;  *(float4*)&As[lr + 32][lc] = a1;
        *(float4*)&Bs[lr][lc] = b0;  *(float4*)&Bs[lr + 32][lc] = b1;
        __syncthreads();
        #pragma unroll
        for (int k = 0; k < 32; k += 4) {
            float4 av[4], bv[4];
            #pragma unroll
            for (int mi = 0; mi < 4; mi++) av[mi] = *(const float4*)&As[ty * 4 + mi][k];
            #pragma unroll
            for (int ni = 0; ni < 4; ni++) bv[ni] = *(const float4*)&Bs[tx * 4 + ni][k];
            #pragma unroll
            for (int mi = 0; mi < 4; mi++)
                #pragma unroll
                for (int ni = 0; ni < 4; ni++)
                    acc[mi][ni] += av[mi].x * bv[ni].x + av[mi].y * bv[ni].y +
                                   av[mi].z * bv[ni].z + av[mi].w * bv[ni].w;
        }
    }
    #pragma unroll
    for (int mi = 0; mi < 4; mi++) {
        float4 v = make_float4(acc[mi][0], acc[mi][1], acc[mi][2], acc[mi][3]);
        *(float4*)&C[(size_t)(bm * 64 + ty * 4 + mi) * WIDTH + bn * 64 + tx * 4] = v;
    }
}

// ---------------- P: partial GEMM ------------------------------------------
// grid 256 = t(0..31) x j(0..7); block 512 (wave = kh*2+nh).
// pbuf[j][t][c(128)][m(64)] fp32 = sum over this WG's 512-k slice.
__global__ __launch_bounds__(512) void partial_kernel(const ushort* __restrict__ cur_in,
                                                      const ushort* __restrict__ Wb,
                                                      float* __restrict__ pbuf) {
    __shared__ char smem[65536];   // A-slice 64KB; fp32 partial[128][65] overlays after MFMA
    const int tid  = threadIdx.x;
    const int w    = tid >> 6;
    const int lane = tid & 63;
    const int lrow = lane & 15;
    const int lq   = lane >> 4;
    const int nh   = w & 1;
    const int kh   = w >> 1;
    const int t    = blockIdx.x >> 3;
    const int j    = blockIdx.x & 7;

    // W fragments: 16 contiguous 1KB-per-instr loads (L2-resident stream)
    const ushort* wbase = Wb + ((((size_t)t * 8 + j) * 8 + w) * 16) * 512 + lane * 8;
    bf16x8 wf[16];
    #pragma unroll
    for (int f = 0; f < 16; f++)
        wf[f] = *(const bf16x8*)(wbase + (size_t)f * 512);

    // stage A k-slice j (contiguous 64KB) into LDS
    const ushort* asrc = cur_in + (size_t)j * 32768;
    #pragma unroll
    for (int it = 0; it < 8; it++) {
        int i2 = w * 8 + it;
        async_copy16(asrc + (size_t)i2 * 512 + lane * 8, smem + i2 * 1024);
    }
    __syncthreads();   // drains Wb loads + A staging

    f32x4 acc[4][4];
    #pragma unroll
    for (int mb = 0; mb < 4; mb++)
        #pragma unroll
        for (int nb = 0; nb < 4; nb++)
            acc[mb][nb] = (f32x4){0.f, 0.f, 0.f, 0.f};

    #pragma unroll
    for (int kc = 0; kc < 4; kc++) {
        const int kvl = kh * 16 + kc * 4 + lq;
        bf16x8 af[4];
        #pragma unroll
        for (int mb = 0; mb < 4; mb++)
            af[mb] = *(const bf16x8*)(smem + ((size_t)kvl * 64 + mb * 16 + lrow) * 16);
        #pragma unroll
        for (int mb = 0; mb < 4; mb++)
            #pragma unroll
            for (int nb = 0; nb < 4; nb++)
                acc[mb][nb] = __builtin_amdgcn_mfma_f32_16x16x32_bf16(af[mb], wf[nb * 4 + kc], acc[mb][nb], 0, 0, 0);
    }
    __syncthreads();   // A-slice dead; partial overlays smem

    // kh-reduce in LDS. C/D layout: c-part = lane&15, m-part = lq*4+r [m89/m91]
    float* partial = (float*)smem;   // [128][65] padded
    if (kh == 0) {
        #pragma unroll
        for (int mb = 0; mb < 4; mb++)
            #pragma unroll
            for (int nb = 0; nb < 4; nb++)
                #pragma unroll
                for (int r = 0; r < 4; r++)
                    partial[(nh * 64 + nb * 16 + lrow) * 65 + mb * 16 + lq * 4 + r] = acc[mb][nb][r];
    }
    __syncthreads();
    if (kh != 0) {
        #pragma unroll
        for (int mb = 0; mb < 4; mb++)
            #pragma unroll
            for (int nb = 0; nb < 4; nb++)
                #pragma unroll
                for (int r = 0; r < 4; r++)
                    atomicAdd(&partial[(nh * 64 + nb * 16 + lrow) * 65 + mb * 16 + lq * 4 + r],
                              acc[mb][nb][r]);
    }
    __syncthreads();

    // write pbuf[j][t][c][m]: fully contiguous 32KB
    float* pd = pbuf + ((size_t)j * 32 + t) * 8192;
    const int c  = tid >> 2;
    const int mf = (tid & 3) * 16;
    #pragma unroll
    for (int i = 0; i < 4; i++) {
        f32x4 v = *(const f32x4*)(partial + c * 65 + mf + i * 4);
        *(f32x4*)(pd + (size_t)c * 64 + mf + i * 4) = v;
    }
}

// ---------------- E: 8-way reduce + scale/bias/erf + state & history -------
// grid 256, block 256. WG bid owns global cols [bid*16, bid*16+16), all 64 m.
__global__ __launch_bounds__(256) void epilogue_kernel(const float* __restrict__ pbuf,
                                                       const float* __restrict__ brow,
                                                       const float* __restrict__ scales,
                                                       ushort* __restrict__ cur_out,
                                                       float* __restrict__ out,
                                                       int h) {
    __shared__ float vals[16 * 64];   // [c][m]
    const int tid = threadIdx.x;
    const int bid = blockIdx.x;
    const int t    = bid >> 3;
    const int csub = (bid & 7) * 16;
    const int c0   = bid * 16;
    const int c  = tid >> 4;
    const int mq = (tid & 15) * 4;

    f32x4 sum = (f32x4){0.f, 0.f, 0.f, 0.f};
    #pragma unroll
    for (int j = 0; j < 8; j++)
        sum += *(const f32x4*)(pbuf + (((size_t)j * 32 + t) * 128 + csub + c) * 64 + mq);

    f32x4 sc = *(const f32x4*)(scales + mq);
    const float bb = brow[c0 + c];
    f32x4 v;
    #pragma unroll
    for (int i = 0; i < 4; i++)
        v[i] = erff(sc[i] * sum[i] + bb) * 0.015625f;   // 1/sqrt(4096)
    *(f32x4*)(vals + c * 64 + mq) = v;
    __syncthreads();

    // blocked bf16 state write: 2 kv-blocks x 64 m, 16B per thread
    if (tid < 128) {
        const int kvb = tid >> 6, m = tid & 63;
        const int kv = (c0 >> 3) + kvb;
        ushort4 lo, hi;
        lo.x = f2bf(vals[(kvb * 8 + 0) * 64 + m]);
        lo.y = f2bf(vals[(kvb * 8 + 1) * 64 + m]);
        lo.z = f2bf(vals[(kvb * 8 + 2) * 64 + m]);
        lo.w = f2bf(vals[(kvb * 8 + 3) * 64 + m]);
        hi.x = f2bf(vals[(kvb * 8 + 4) * 64 + m]);
        hi.y = f2bf(vals[(kvb * 8 + 5) * 64 + m]);
        hi.z = f2bf(vals[(kvb * 8 + 6) * 64 + m]);
        hi.w = f2bf(vals[(kvb * 8 + 7) * 64 + m]);
        ushort* dst = cur_out + ((size_t)kv * 64 + m) * 8;
        *(ushort4*)dst = lo;
        *(ushort4*)(dst + 4) = hi;
    }
    if (h >= 0) {
        const int m  = tid >> 2;
        const int cq = (tid & 3) * 4;
        float4 o;
        o.x = vals[(cq + 0) * 64 + m];
        o.y = vals[(cq + 1) * 64 + m];
        o.z = vals[(cq + 2) * 64 + m];
        o.w = vals[(cq + 3) * 64 + m];
        *(float4*)(out + ((size_t)m * NHIST + h) * WIDTH + c0 + cq) = o;
    }
}

extern "C" void kernel_launch(void* const* d_in, const int* in_sizes, int n_in,
                              void* d_out, int out_size, void* d_ws, size_t ws_size,
                              hipStream_t stream) {
    const float* x      = (const float*)d_in[0];
    const float* biases = (const float*)d_in[1];
    const float* W      = (const float*)d_in[2];
    const float* W_bias = (const float*)d_in[3];
    const float* scales = (const float*)d_in[4];
    float* out = (float*)d_out;

    char* ws = (char*)d_ws;
    ushort* Wb   = (ushort*)ws;                                   // 32 MB
    float*  b    = (float*)(ws + ((size_t)32 << 20));             // 8 MB
    float*  pbuf = (float*)(ws + ((size_t)40 << 20));             // 8 MB
    ushort* cur0 = (ushort*)(ws + ((size_t)48 << 20));            // 512 KB
    ushort* cur1 = (ushort*)(ws + ((size_t)48 << 20) + (512 << 10));

    convert_w_kernel<<<8192, 256, 0, stream>>>(W, Wb);
    init_curr_kernel<<<128, 256, 0, stream>>>(x, cur0);
    bias_gemm_kernel<<<dim3(64, 8), 256, 0, stream>>>(biases, W_bias, b);

    ushort* curs[2] = {cur0, cur1};
    for (int d = 0; d < DEPTH; d++) {
        const ushort* cin = curs[d & 1];
        ushort* cout = curs[(d + 1) & 1];
        int h = d - (DEPTH - NHIST);
        partial_kernel<<<256, 512, 0, stream>>>(cin, Wb, pbuf);
        epilogue_kernel<<<256, 256, 0, stream>>>(pbuf, b + (size_t)d * WIDTH,
                                                 scales, cout, out, h);
    }
}

// Round 4
// 7928.036 us; speedup vs baseline: 9.0188x; 3.0266x over previous
//
#include <hip/hip_runtime.h>
#include <cstdint>
#include <cstddef>

#define WIDTH 4096
#define DEPTH 512
#define NHIST 20
#define NWG 256
#define NTHR 512

typedef __attribute__((ext_vector_type(4))) float f32x4;
typedef __attribute__((ext_vector_type(2))) float f32x2;
typedef __attribute__((ext_vector_type(8))) short bf16x8;

__device__ __forceinline__ ushort f2bf(float f) {
    uint32_t u = __float_as_uint(f);
    u += 0x7FFFu + ((u >> 16) & 1u);   // round-to-nearest-even
    return (ushort)(u >> 16);
}

// ---------------- curr0 = tile(x), blocked bf16 layout ----------------------
// cur element (m, c) at (( (c>>3)*64 + m )*8 + (c&7))
__global__ __launch_bounds__(256) void init_curr_kernel(const float* __restrict__ x,
                                                        ushort* __restrict__ cur) {
    int g = blockIdx.x * 256 + threadIdx.x;   // 0..32767
    int kv = g >> 6, m = g & 63;
    ushort4 lo, hi;
    lo.x = f2bf(x[kv * 8 + 0]); lo.y = f2bf(x[kv * 8 + 1]);
    lo.z = f2bf(x[kv * 8 + 2]); lo.w = f2bf(x[kv * 8 + 3]);
    hi.x = f2bf(x[kv * 8 + 4]); hi.y = f2bf(x[kv * 8 + 5]);
    hi.z = f2bf(x[kv * 8 + 6]); hi.w = f2bf(x[kv * 8 + 7]);
    ushort* dst = cur + ((size_t)kv * 64 + m) * 8;
    *(ushort4*)dst = lo;
    *(ushort4*)(dst + 4) = hi;
}

// ---------------- zero the flag array ---------------------------------------
__global__ __launch_bounds__(256) void zero_flags_kernel(int* __restrict__ flags) {
    flags[blockIdx.x * 256 + threadIdx.x] = 0;
}

// ---------------- bias GEMM, fp32 vector ALU --------------------------------
__global__ __launch_bounds__(256) void bias_gemm_kernel(const float* __restrict__ A,
                                                        const float* __restrict__ B,
                                                        float* __restrict__ C) {
    __shared__ float As[64][36];
    __shared__ float Bs[64][36];
    const int bm = blockIdx.y;
    const int bn = blockIdx.x;
    const int t  = threadIdx.x;
    const int tx = t & 15, ty = t >> 4;
    const int lr = t >> 3;
    const int lc = (t & 7) * 4;

    float acc[4][4] = {};
    for (int k0 = 0; k0 < WIDTH; k0 += 32) {
        float4 a0 = *(const float4*)&A[(size_t)(bm * 64 + lr) * WIDTH + k0 + lc];
        float4 a1 = *(const float4*)&A[(size_t)(bm * 64 + lr + 32) * WIDTH + k0 + lc];
        float4 b0 = *(const float4*)&B[(size_t)(bn * 64 + lr) * WIDTH + k0 + lc];
        float4 b1 = *(const float4*)&B[(size_t)(bn * 64 + lr + 32) * WIDTH + k0 + lc];
        __syncthreads();
        *(float4*)&As[lr][lc] = a0;  *(float4*)&As[lr + 32][lc] = a1;
        *(float4*)&Bs[lr][lc] = b0;  *(float4*)&Bs[lr + 32][lc] = b1;
        __syncthreads();
        #pragma unroll
        for (int k = 0; k < 32; k += 4) {
            float4 av[4], bv[4];
            #pragma unroll
            for (int mi = 0; mi < 4; mi++) av[mi] = *(const float4*)&As[ty * 4 + mi][k];
            #pragma unroll
            for (int ni = 0; ni < 4; ni++) bv[ni] = *(const float4*)&Bs[tx * 4 + ni][k];
            #pragma unroll
            for (int mi = 0; mi < 4; mi++)
                #pragma unroll
                for (int ni = 0; ni < 4; ni++)
                    acc[mi][ni] += av[mi].x * bv[ni].x + av[mi].y * bv[ni].y +
                                   av[mi].z * bv[ni].z + av[mi].w * bv[ni].w;
        }
    }
    #pragma unroll
    for (int mi = 0; mi < 4; mi++) {
        float4 v = make_float4(acc[mi][0], acc[mi][1], acc[mi][2], acc[mi][3]);
        *(float4*)&C[(size_t)(bm * 64 + ty * 4 + mi) * WIDTH + bn * 64 + tx * 4] = v;
    }
}

// ---------------- persistent reservoir: 256 WGs x 512 thr -------------------
// WG t owns output cols [t*16, t*16+16), full K. Wave w owns k in [w*512, ..+512).
// W block (16 x 4096) held in registers (wf[16]) for the whole kernel.
// Sync: flag[t] = d+1 (release) after step d; wave 0 polls all 256 flags >= d.
__global__ __launch_bounds__(NTHR, 2) void reservoir_kernel(
    const float* __restrict__ W,
    const float* __restrict__ scales,
    const float* __restrict__ b,      // [512][4096] fp32
    float* __restrict__ out,          // [64][20][4096] fp32
    ushort* __restrict__ cur0,
    ushort* __restrict__ cur1,
    int* __restrict__ flags)          // 256 flags, stride 16 ints (64 B)
{
    __shared__ float partial[8][16][72];   // [wave][c][m] padded to 72 (16B-aligned rows)
    __shared__ float vals[16][68];         // [c][m]

    const int tid  = threadIdx.x;
    const int w    = tid >> 6;
    const int lane = tid & 63;
    const int lrow = lane & 15;
    const int lq   = lane >> 4;
    const int t    = blockIdx.x;
    const int c0   = t * 16;

    // fixed epilogue mapping: thread -> (col c=ec, rows em, em+1)
    const int ec = tid >> 5;            // 0..15
    const int em = (tid & 31) * 2;      // 0,2,..,62
    const float s0 = scales[em];
    const float s1 = scales[em + 1];

    // ---- load this WG's W rows into bf16 fragments (once) ----
    bf16x8 wf[16];
    #pragma unroll
    for (int kc = 0; kc < 16; kc++) {
        const float* src = W + (size_t)(c0 + lrow) * WIDTH + w * 512 + kc * 32 + lq * 8;
        float4 f0 = *(const float4*)src;
        float4 f1 = *(const float4*)(src + 4);
        bf16x8 v;
        v[0] = (short)f2bf(f0.x); v[1] = (short)f2bf(f0.y);
        v[2] = (short)f2bf(f0.z); v[3] = (short)f2bf(f0.w);
        v[4] = (short)f2bf(f1.x); v[5] = (short)f2bf(f1.y);
        v[6] = (short)f2bf(f1.z); v[7] = (short)f2bf(f1.w);
        wf[kc] = v;
    }

    ushort* curs[2] = {cur0, cur1};

    for (int d = 0; d < DEPTH; d++) {
        // ---- wait for all WGs to have finished step d-1 ----
        if (d > 0) {
            if (w == 0) {
                for (;;) {
                    bool ok = true;
                    #pragma unroll
                    for (int q = 0; q < 4; q++) {
                        int v = __hip_atomic_load(flags + (lane * 4 + q) * 16,
                                                  __ATOMIC_RELAXED, __HIP_MEMORY_SCOPE_AGENT);
                        ok = ok && (v >= d);
                    }
                    if (__all(ok)) break;
                    __builtin_amdgcn_s_sleep(8);
                }
            }
            if (tid == 0)
                (void)__hip_atomic_load(flags, __ATOMIC_ACQUIRE, __HIP_MEMORY_SCOPE_AGENT);
            __syncthreads();   // all threads gated; caches invalidated
        }

        const ushort* cin  = curs[d & 1];
        ushort*       cout = curs[(d + 1) & 1];

        // prefetch this step's bias entry (used post-MFMA; latency hidden)
        const float bv = b[(size_t)d * WIDTH + c0 + ec];

        // ---- MFMA over this wave's 512-k slice, direct loads from cur ----
        f32x4 acc[4];
        #pragma unroll
        for (int mb = 0; mb < 4; mb++) acc[mb] = (f32x4){0.f, 0.f, 0.f, 0.f};

        #pragma unroll 4
        for (int kc = 0; kc < 16; kc++) {
            const int kv = w * 64 + kc * 4 + lq;
            bf16x8 af[4];
            #pragma unroll
            for (int mb = 0; mb < 4; mb++)
                af[mb] = *(const bf16x8*)(cin + ((size_t)kv * 64 + mb * 16 + lrow) * 8);
            #pragma unroll
            for (int mb = 0; mb < 4; mb++)
                acc[mb] = __builtin_amdgcn_mfma_f32_16x16x32_bf16(af[mb], wf[kc], acc[mb], 0, 0, 0);
        }

        // ---- wave partials to LDS. C/D: c = lane&15, m = lq*4+r (+16*mb) ----
        #pragma unroll
        for (int mb = 0; mb < 4; mb++)
            *(f32x4*)&partial[w][lrow][mb * 16 + lq * 4] = acc[mb];
        __syncthreads();

        // ---- 8-way reduce + scale/bias/erf ----
        float sum0 = 0.f, sum1 = 0.f;
        #pragma unroll
        for (int ww = 0; ww < 8; ww++) {
            sum0 += partial[ww][ec][em];
            sum1 += partial[ww][ec][em + 1];
        }
        float v0 = erff(s0 * sum0 + bv) * 0.015625f;   // 1/sqrt(4096)
        float v1 = erff(s1 * sum1 + bv) * 0.015625f;
        *(f32x2*)&vals[ec][em] = (f32x2){v0, v1};
        __syncthreads();

        // ---- state stripe: 8B write-through atomics (blocked layout) ----
        if (tid < 256) {
            const int m    = tid & 63;
            const int kvb  = (tid >> 6) & 1;
            const int half = tid >> 7;
            const int cb   = kvb * 8 + half * 4;
            uint64_t pack =
                 (uint64_t)f2bf(vals[cb + 0][m])
               | ((uint64_t)f2bf(vals[cb + 1][m]) << 16)
               | ((uint64_t)f2bf(vals[cb + 2][m]) << 32)
               | ((uint64_t)f2bf(vals[cb + 3][m]) << 48);
            uint64_t* dst = (uint64_t*)(cout + ((size_t)(t * 2 + kvb) * 64 + m) * 8 + half * 4);
            __hip_atomic_store(dst, pack, __ATOMIC_RELAXED, __HIP_MEMORY_SCOPE_AGENT);
        }

        // ---- history: 8B write-through atomics (avoids cross-XCD false sharing) ----
        const int h = d - (DEPTH - NHIST);
        if (h >= 0) {
            const int m = tid >> 3;
            const int c = (tid & 7) * 2;
            union { uint64_t u; float f[2]; } p;
            p.f[0] = vals[c][m];
            p.f[1] = vals[c + 1][m];
            uint64_t* dst = (uint64_t*)(out + ((size_t)m * NHIST + h) * WIDTH + c0 + c);
            __hip_atomic_store(dst, p.u, __ATOMIC_RELAXED, __HIP_MEMORY_SCOPE_AGENT);
        }

        __syncthreads();   // per-wave vmcnt drained at barrier -> all WG stores complete
        if (tid == 0)
            __hip_atomic_store(flags + t * 16, d + 1,
                               __ATOMIC_RELEASE, __HIP_MEMORY_SCOPE_AGENT);
    }
}

extern "C" void kernel_launch(void* const* d_in, const int* in_sizes, int n_in,
                              void* d_out, int out_size, void* d_ws, size_t ws_size,
                              hipStream_t stream) {
    const float* x      = (const float*)d_in[0];
    const float* biases = (const float*)d_in[1];
    const float* W      = (const float*)d_in[2];
    const float* W_bias = (const float*)d_in[3];
    const float* scales = (const float*)d_in[4];
    float* out = (float*)d_out;

    char* ws = (char*)d_ws;
    float*  b    = (float*)ws;                                    // 8 MB
    ushort* cur0 = (ushort*)(ws + ((size_t)8 << 20));             // 512 KB
    ushort* cur1 = (ushort*)(ws + ((size_t)8 << 20) + (512 << 10));
    int*    flags = (int*)(ws + ((size_t)9 << 20));               // 16 KB

    init_curr_kernel<<<128, 256, 0, stream>>>(x, cur0);
    zero_flags_kernel<<<16, 256, 0, stream>>>(flags);
    bias_gemm_kernel<<<dim3(64, 8), 256, 0, stream>>>(biases, W_bias, b);

    void* args[] = {(void*)&W, (void*)&scales, (void*)&b, (void*)&out,
                    (void*)&cur0, (void*)&cur1, (void*)&flags};
    hipLaunchCooperativeKernel((const void*)reservoir_kernel, dim3(NWG), dim3(NTHR),
                               args, 0, stream);
}

// Round 6
// 6625.182 us; speedup vs baseline: 10.7923x; 1.1967x over previous
//
#include <hip/hip_runtime.h>
#include <cstdint>
#include <cstddef>

#define WIDTH 4096
#define DEPTH 512
#define NHIST 20
#define NWG 256
#define NTHR 1024

typedef __attribute__((ext_vector_type(4))) float f32x4;
typedef __attribute__((ext_vector_type(8))) short bf16x8;

__device__ __forceinline__ ushort f2bf(float f) {
    uint32_t u = __float_as_uint(f);
    u += 0x7FFFu + ((u >> 16) & 1u);   // round-to-nearest-even
    return (ushort)(u >> 16);
}

// cur blocked layout: element (m, c): kv=c>>3, unit = ((kv>>2)*4 + (m>>4))*64
//   + (kv&3)*16 + (m&15); ushort offset = unit*8 + (c&7).
// -> wave-w fragment f = kc*4+mb occupies units [(w*8+kc)*4+mb]*64 .. +64,
//    i.e. ushort offset (w*16384 + f*512) + (lq*16+lrow)*8: one contiguous
//    1KB burst per load instruction (lane-linear).

// ---------------- curr0 = tile(x) ------------------------------------------
__global__ __launch_bounds__(256) void init_curr_kernel(const float* __restrict__ x,
                                                        ushort* __restrict__ cur) {
    int g = blockIdx.x * 256 + threadIdx.x;   // 0..32767
    int kv = g >> 6, m = g & 63;
    int unit = ((kv >> 2) * 4 + (m >> 4)) * 64 + (kv & 3) * 16 + (m & 15);
    ushort4 lo, hi;
    lo.x = f2bf(x[kv * 8 + 0]); lo.y = f2bf(x[kv * 8 + 1]);
    lo.z = f2bf(x[kv * 8 + 2]); lo.w = f2bf(x[kv * 8 + 3]);
    hi.x = f2bf(x[kv * 8 + 4]); hi.y = f2bf(x[kv * 8 + 5]);
    hi.z = f2bf(x[kv * 8 + 6]); hi.w = f2bf(x[kv * 8 + 7]);
    ushort* dst = cur + (size_t)unit * 8;
    *(ushort4*)dst = lo;
    *(ushort4*)(dst + 4) = hi;
}

// ---------------- zero flags + gflag ----------------------------------------
__global__ __launch_bounds__(256) void zero_flags_kernel(int* __restrict__ flags) {
    flags[blockIdx.x * 256 + threadIdx.x] = 0;   // grid 32 -> 8192 ints
}

// ---------------- bias GEMM, fp32 vector ALU --------------------------------
__global__ __launch_bounds__(256) void bias_gemm_kernel(const float* __restrict__ A,
                                                        const float* __restrict__ B,
                                                        float* __restrict__ C) {
    __shared__ float As[64][36];
    __shared__ float Bs[64][36];
    const int bm = blockIdx.y;
    const int bn = blockIdx.x;
    const int t  = threadIdx.x;
    const int tx = t & 15, ty = t >> 4;
    const int lr = t >> 3;
    const int lc = (t & 7) * 4;

    float acc[4][4] = {};
    for (int k0 = 0; k0 < WIDTH; k0 += 32) {
        float4 a0 = *(const float4*)&A[(size_t)(bm * 64 + lr) * WIDTH + k0 + lc];
        float4 a1 = *(const float4*)&A[(size_t)(bm * 64 + lr + 32) * WIDTH + k0 + lc];
        float4 b0 = *(const float4*)&B[(size_t)(bn * 64 + lr) * WIDTH + k0 + lc];
        float4 b1 = *(const float4*)&B[(size_t)(bn * 64 + lr + 32) * WIDTH + k0 + lc];
        __syncthreads();
        *(float4*)&As[lr][lc] = a0;  *(float4*)&As[lr + 32][lc] = a1;
        *(float4*)&Bs[lr][lc] = b0;  *(float4*)&Bs[lr + 32][lc] = b1;
        __syncthreads();
        #pragma unroll
        for (int k = 0; k < 32; k += 4) {
            float4 av[4], bv[4];
            #pragma unroll
            for (int mi = 0; mi < 4; mi++) av[mi] = *(const float4*)&As[ty * 4 + mi][k];
            #pragma unroll
            for (int ni = 0; ni < 4; ni++) bv[ni] = *(const float4*)&Bs[tx * 4 + ni][k];
            #pragma unroll
            for (int mi = 0; mi < 4; mi++)
                #pragma unroll
                for (int ni = 0; ni < 4; ni++)
                    acc[mi][ni] += av[mi].x * bv[ni].x + av[mi].y * bv[ni].y +
                                   av[mi].z * bv[ni].z + av[mi].w * bv[ni].w;
        }
    }
    #pragma unroll
    for (int mi = 0; mi < 4; mi++) {
        float4 v = make_float4(acc[mi][0], acc[mi][1], acc[mi][2], acc[mi][3]);
        *(float4*)&C[(size_t)(bm * 64 + ty * 4 + mi) * WIDTH + bn * 64 + tx * 4] = v;
    }
}

// ---------------- persistent reservoir: 256 WGs x 1024 thr ------------------
// WG t owns cols [t*16, t*16+16), full K. Wave w (16) owns k in [w*256, +256).
// Barrier: flags[t]=d+1 (release); WG0/wave0 collects -> gflag=d+1; all poll gflag.
__global__ __launch_bounds__(NTHR, 4) void reservoir_kernel(
    const float* __restrict__ W,
    const float* __restrict__ scales,
    const float* __restrict__ b,      // [512][4096] fp32
    float* __restrict__ out,          // [64][20][4096] fp32
    ushort* __restrict__ cur0,
    ushort* __restrict__ cur1,
    int* __restrict__ flags)          // [256] stride 16 ints; gflag at +4096
{
    __shared__ float partial[16][16][72];   // [wave][c][m] 73.7 KB
    __shared__ float vals[16][65];          // [c][m] padded 65 (history-read banks)

    const int tid  = threadIdx.x;
    const int w    = tid >> 6;
    const int lane = tid & 63;
    const int lrow = lane & 15;
    const int lq   = lane >> 4;
    const int t    = blockIdx.x;
    const int c0   = t * 16;
    int* gflag = flags + 4096;

    // epilogue mapping: thread -> (col ec, row em); one output each
    const int ec = tid >> 6;     // == w
    const int em = lane;
    const float sc_e = scales[em];

    // ---- W rows -> bf16 fragments (held all 512 steps) ----
    bf16x8 wf[8];
    #pragma unroll
    for (int kc = 0; kc < 8; kc++) {
        const float* src = W + (size_t)(c0 + lrow) * WIDTH + w * 256 + kc * 32 + lq * 8;
        float4 f0 = *(const float4*)src;
        float4 f1 = *(const float4*)(src + 4);
        bf16x8 v;
        v[0] = (short)f2bf(f0.x); v[1] = (short)f2bf(f0.y);
        v[2] = (short)f2bf(f0.z); v[3] = (short)f2bf(f0.w);
        v[4] = (short)f2bf(f1.x); v[5] = (short)f2bf(f1.y);
        v[6] = (short)f2bf(f1.z); v[7] = (short)f2bf(f1.w);
        wf[kc] = v;
    }

    ushort* curs[2] = {cur0, cur1};

    for (int d = 0; d < DEPTH; d++) {
        // ---- wait for step d-1 completion (single broadcast line) ----
        if (d > 0) {
            if (tid == 0) {
                while (__hip_atomic_load(gflag, __ATOMIC_RELAXED, __HIP_MEMORY_SCOPE_AGENT) < d)
                    __builtin_amdgcn_s_sleep(2);
                (void)__hip_atomic_load(gflag, __ATOMIC_ACQUIRE, __HIP_MEMORY_SCOPE_AGENT);
            }
            __syncthreads();
        }

        const ushort* cin  = curs[d & 1];
        ushort*       cout = curs[(d + 1) & 1];
        const float bv = b[(size_t)d * WIDTH + c0 + ec];   // early; hidden under MFMA

        // ---- MFMA over this wave's 256-k slice; 1KB-burst loads, dbuf regs ----
        f32x4 acc[4];
        #pragma unroll
        for (int mb = 0; mb < 4; mb++) acc[mb] = (f32x4){0.f, 0.f, 0.f, 0.f};

        // fragment f = kc*4+mb at ushort offset w*16384 + f*512 + lane-linear
        const ushort* abase = cin + (size_t)w * 16384 + ((size_t)lq * 16 + lrow) * 8;
        bf16x8 afA[4], afB[4];
        #pragma unroll
        for (int mb = 0; mb < 4; mb++)
            afA[mb] = *(const bf16x8*)(abase + (size_t)mb * 512);

        #pragma unroll
        for (int kc = 0; kc < 8; kc += 2) {
            #pragma unroll
            for (int mb = 0; mb < 4; mb++)
                afB[mb] = *(const bf16x8*)(abase + ((size_t)(kc + 1) * 4 + mb) * 512);
            #pragma unroll
            for (int mb = 0; mb < 4; mb++)
                acc[mb] = __builtin_amdgcn_mfma_f32_16x16x32_bf16(afA[mb], wf[kc], acc[mb], 0, 0, 0);
            if (kc + 2 < 8) {
                #pragma unroll
                for (int mb = 0; mb < 4; mb++)
                    afA[mb] = *(const bf16x8*)(abase + ((size_t)(kc + 2) * 4 + mb) * 512);
            }
            #pragma unroll
            for (int mb = 0; mb < 4; mb++)
                acc[mb] = __builtin_amdgcn_mfma_f32_16x16x32_bf16(afB[mb], wf[kc + 1], acc[mb], 0, 0, 0);
        }

        // ---- wave partials. C/D: c = lane&15, m = lq*4+r (+16*mb) [m89/m91] ----
        #pragma unroll
        for (int mb = 0; mb < 4; mb++)
            *(f32x4*)&partial[w][lrow][mb * 16 + lq * 4] = acc[mb];
        __syncthreads();

        // ---- 16-way reduce + scale/bias/erf (one output per thread) ----
        {
            float sum = 0.f;
            #pragma unroll
            for (int ww = 0; ww < 16; ww++) sum += partial[ww][ec][em];
            vals[ec][em] = erff(sc_e * sum + bv) * 0.015625f;   // 1/sqrt(4096)
        }
        __syncthreads();

        // ---- state stripe: 8B write-through atomics, blocked layout ----
        if (tid < 256) {
            const int m    = tid & 63;
            const int kvb  = (tid >> 6) & 1;
            const int half = tid >> 7;
            const int cb   = kvb * 8 + half * 4;
            const int kv   = t * 2 + kvb;
            uint64_t pack =
                 (uint64_t)f2bf(vals[cb + 0][m])
               | ((uint64_t)f2bf(vals[cb + 1][m]) << 16)
               | ((uint64_t)f2bf(vals[cb + 2][m]) << 32)
               | ((uint64_t)f2bf(vals[cb + 3][m]) << 48);
            int unit = ((kv >> 2) * 4 + (m >> 4)) * 64 + (kv & 3) * 16 + (m & 15);
            uint64_t* dst = (uint64_t*)(cout + (size_t)unit * 8 + half * 4);
            __hip_atomic_store(dst, pack, __ATOMIC_RELAXED, __HIP_MEMORY_SCOPE_AGENT);
        }

        // ---- history: 8B write-through atomics ----
        const int h = d - (DEPTH - NHIST);
        if (h >= 0 && tid < 512) {
            const int m = tid >> 3;
            const int c = (tid & 7) * 2;
            union { uint64_t u; float f[2]; } p;
            p.f[0] = vals[c][m];
            p.f[1] = vals[c + 1][m];
            uint64_t* dst = (uint64_t*)(out + ((size_t)m * NHIST + h) * WIDTH + c0 + c);
            __hip_atomic_store(dst, p.u, __ATOMIC_RELAXED, __HIP_MEMORY_SCOPE_AGENT);
        }

        __syncthreads();   // per-wave vmcnt drained -> all WG stores complete
        if (tid == 0)
            __hip_atomic_store(flags + t * 16, d + 1,
                               __ATOMIC_RELEASE, __HIP_MEMORY_SCOPE_AGENT);

        // ---- WG0 wave0 collects 256 arrivals, publishes broadcast line ----
        if (t == 0 && w == 0) {
            for (;;) {
                bool ok = true;
                #pragma unroll
                for (int q = 0; q < 4; q++) {
                    int v = __hip_atomic_load(flags + (lane * 4 + q) * 16,
                                              __ATOMIC_RELAXED, __HIP_MEMORY_SCOPE_AGENT);
                    ok = ok && (v >= d + 1);
                }
                if (__all(ok)) break;
                __builtin_amdgcn_s_sleep(2);
            }
            if (lane == 0) {
                (void)__hip_atomic_load(flags, __ATOMIC_ACQUIRE, __HIP_MEMORY_SCOPE_AGENT);
                __hip_atomic_store(gflag, d + 1, __ATOMIC_RELEASE, __HIP_MEMORY_SCOPE_AGENT);
            }
        }
    }
}

extern "C" void kernel_launch(void* const* d_in, const int* in_sizes, int n_in,
                              void* d_out, int out_size, void* d_ws, size_t ws_size,
                              hipStream_t stream) {
    const float* x      = (const float*)d_in[0];
    const float* biases = (const float*)d_in[1];
    const float* W      = (const float*)d_in[2];
    const float* W_bias = (const float*)d_in[3];
    const float* scales = (const float*)d_in[4];
    float* out = (float*)d_out;

    char* ws = (char*)d_ws;
    float*  b    = (float*)ws;                                    // 8 MB
    ushort* cur0 = (ushort*)(ws + ((size_t)8 << 20));             // 512 KB
    ushort* cur1 = (ushort*)(ws + ((size_t)8 << 20) + (512 << 10));
    int*    flags = (int*)(ws + ((size_t)9 << 20));               // 32 KB (flags+gflag)

    init_curr_kernel<<<128, 256, 0, stream>>>(x, cur0);
    zero_flags_kernel<<<32, 256, 0, stream>>>(flags);
    bias_gemm_kernel<<<dim3(64, 8), 256, 0, stream>>>(biases, W_bias, b);

    void* args[] = {(void*)&W, (void*)&scales, (void*)&b, (void*)&out,
                    (void*)&cur0, (void*)&cur1, (void*)&flags};
    hipLaunchCooperativeKernel((const void*)reservoir_kernel, dim3(NWG), dim3(NTHR),
                               args, 0, stream);
}